// Round 3
// baseline (160.757 us; speedup 1.0000x reference)
//
#include <hip/hip_runtime.h>
#include <math.h>

#define N     4096
#define NIMG  2048
#define TX    56          // output tile width
#define TY    56          // output tile height
#define DW    64          // D-region width  = TX + 8 (1 lane per column)
#define DH    64          // D-region height = TY + 8
#define IPP   35          // img patch pitch (odd)
#define STP   65          // ST pitch over rows (odd)
#define VP    65          // V pitch (odd)

// Gaussian kernel sigma=1, r=4 (double-precision eval of reference formula)
#define KW0 0.00013383063f
#define KW1 0.00443186160f
#define KW2 0.05399112800f
#define KW3 0.24197144000f
#define KW4 0.39894346870f

__device__ __forceinline__ int symi(int g) {
    g = (g < 0) ? (-1 - g) : g;
    g = (g >= N) ? (2 * N - 1 - g) : g;
    return g;
}

__global__ __launch_bounds__(256, 5)
void TensorAugment_79216376807666_kernel(const float* __restrict__ img,
                                         const float* __restrict__ noise,
                                         float* __restrict__ out) {
    __shared__ float ST[DW * STP];      // D tile, column-major [c][row]   16.6 KB
    __shared__ float UN[TY * VP];       // union: IP (stages 0-1), V (2-3) 14.6 KB
    float* const IP = UN;
    float* const V  = UN;

    const int tid  = threadIdx.x;
    const int lane = tid & 63;
    const int wave = tid >> 6;
    const int bx = blockIdx.x, by = blockIdx.y;
    const int x0 = bx * TX;
    const int y0 = by * TY;
    const bool interior = (bx >= 1) && (bx <= 72) && (by >= 1) && (by <= 72);

    const float kk[9] = {KW0, KW1, KW2, KW3, KW4, KW3, KW2, KW1, KW0};

    // ---- block-uniform staged ranges (generic; exact for interior too) ----
    int gxa = x0 - 4, gxb = x0 + DW - 5;
    int mxa = symi(gxa), mxb = symi(gxb);
    int gxmin = min(mxa, mxb), gxmax = max(mxa, mxb);
    if (gxa <= 0) gxmin = 0;
    if (gxb >= N - 1) gxmax = N - 1;
    int umin = (N - 1) - gxmax, umax = (N - 1) - gxmin;
    int r0min = (umin - 1) >> 1;
    int r0max = (umax - 1) >> 1;
    int nrows = r0max - r0min + 2;       // <= 34

    int gya = y0 - 4, gyb = y0 + DH - 5;
    int mya = symi(gya), myb = symi(gyb);
    int gymin = min(mya, myb), gymax = max(mya, myb);
    if (gya <= 0) gymin = 0;
    if (gyb >= N - 1) gymax = N - 1;
    int c0min = (gymin - 1) >> 1;
    int c0max = (gymax - 1) >> 1;
    int ncols = c0max - c0min + 2;       // <= 34

    // ---- stage 0: img patch -> IP (clamped; clamps are no-ops interior) ----
    {
        int c = tid & 31;
        for (int r = tid >> 5; r < nrows; r += 8) {
            int ir = min(max(r0min + r, 0), NIMG - 1);
            int ic = min(max(c0min + c, 0), NIMG - 1);
            IP[r * IPP + c] = img[ir * NIMG + ic];
            if (c < ncols - 32) {
                int ic2 = min(max(c0min + 32 + c, 0), NIMG - 1);
                IP[r * IPP + 32 + c] = img[ir * NIMG + ic2];
            }
        }
    }
    __syncthreads();

    // ---- stage 1: D = bilinear(rot) + 0.01*noise, column-major into ST ----
    if (interior) {
        // lane g handles D cols 4g..4g+3 of one row; 4 rows per wave-quad.
        int g  = lane & 15;
        int rr = lane >> 4;
        int sbase = (30 - 2 * g) * IPP;       // staged row (m-2)
        const float* npz = noise + (size_t)(y0 - 4) * N + (x0 - 4) + 4 * g;
#pragma unroll
        for (int it = 0; it < 4; ++it) {
            int row = it * 16 + wave * 4 + rr;         // 0..63
            int jc  = (row + 1) >> 1;
            float wc1 = (row & 1) ? 0.25f : 0.75f;
            float wc0 = 1.0f - wc1;
            float4 nv = *reinterpret_cast<const float4*>(npz + (size_t)row * N);
            int b = sbase + jc;
            float t0 = fmaf(wc0, IP[b],           wc1 * IP[b + 1]);            // m-2
            float t1 = fmaf(wc0, IP[b + IPP],     wc1 * IP[b + IPP + 1]);      // m-1
            float t2 = fmaf(wc0, IP[b + 2 * IPP], wc1 * IP[b + 2 * IPP + 1]);  // m
            float t3 = fmaf(wc0, IP[b + 3 * IPP], wc1 * IP[b + 3 * IPP + 1]);  // m+1
            float D0 = fmaf(0.75f, t2, 0.25f * t3);
            float D1 = fmaf(0.25f, t1, 0.75f * t2);
            float D2 = fmaf(0.75f, t1, 0.25f * t2);
            float D3 = fmaf(0.25f, t0, 0.75f * t1);
            int sb = (4 * g) * STP + row;
            ST[sb]           = fmaf(0.01f, nv.x, D0);
            ST[sb + STP]     = fmaf(0.01f, nv.y, D1);
            ST[sb + 2 * STP] = fmaf(0.01f, nv.z, D2);
            ST[sb + 3 * STP] = fmaf(0.01f, nv.w, D3);
        }
    } else {
        // generic edge path (scalar, symmetric mapping)
        int c   = lane;
        int gxm = symi(x0 - 4 + c);
        int u   = (N - 1) - gxm;
        int r0  = (u - 1) >> 1;
        float wr1 = (u & 1) ? 0.25f : 0.75f;
        float wr0 = 1.0f - wr1;
        int a0 = (r0 - r0min) * IPP;
#pragma unroll
        for (int k = 0; k < 16; ++k) {
            int row = wave + 4 * k;                    // 0..63
            int gym = symi(y0 - 4 + row);
            int c0  = (gym - 1) >> 1;
            float wc1 = (gym & 1) ? 0.25f : 0.75f;
            float wc0 = 1.0f - wc1;
            int jc = c0 - c0min;
            float nv = noise[(size_t)gym * N + gxm];
            float f0 = IP[a0 + jc],       f1 = IP[a0 + jc + 1];
            float f2 = IP[a0 + IPP + jc], f3 = IP[a0 + IPP + jc + 1];
            float top = fmaf(wc0, f0, wc1 * f1);
            float bot = fmaf(wc0, f2, wc1 * f3);
            ST[c * STP + row] = fmaf(wr0, top, wr1 * bot) + 0.01f * nv;
        }
    }
    __syncthreads();   // ST ready; IP dead (UN may be overwritten as V)

    // ---- stage 2: vertical blur, sliding window (14 outputs/thread) ----
    {
        int c  = lane;
        int rb = wave * 14;                            // 0,14,28,42
        float win[22];
        int ab = c * STP + rb;
#pragma unroll
        for (int k = 0; k < 22; ++k) win[k] = ST[ab + k];
#pragma unroll
        for (int j = 0; j < 14; ++j) {
            float acc = 0.0f;
#pragma unroll
            for (int i = 0; i < 9; ++i) acc = fmaf(kk[i], win[j + i], acc);
            V[(rb + j) * VP + c] = acc;
        }
    }
    __syncthreads();

    // ---- stage 3: horizontal blur + relu + log1p + direct store ----
    {
        int r = tid >> 2;                              // 0..63
        int s = tid & 3;                               // segment of 14 cols
        if (r < TY) {
            float w2[22];
            int vb = r * VP + s * 14;
#pragma unroll
            for (int k = 0; k < 22; ++k) w2[k] = V[vb + k];
            float res[14];
#pragma unroll
            for (int j = 0; j < 14; ++j) {
                float acc = 0.0f;
#pragma unroll
                for (int i = 0; i < 9; ++i) acc = fmaf(kk[i], w2[j + i], acc);
                acc = fmaxf(acc, 0.0f);
                res[j] = __logf(1.0f + acc);
            }
            if (interior) {
                float2* op = reinterpret_cast<float2*>(out + (size_t)(y0 + r) * N + x0 + s * 14);
#pragma unroll
                for (int j2 = 0; j2 < 7; ++j2)
                    op[j2] = make_float2(res[2 * j2], res[2 * j2 + 1]);
            } else {
                int gy = y0 + r;
                if (gy < N) {
#pragma unroll
                    for (int j = 0; j < 14; ++j) {
                        int gx = x0 + s * 14 + j;
                        if (gx < N) out[(size_t)gy * N + gx] = res[j];
                    }
                }
            }
        }
    }
}

extern "C" void kernel_launch(void* const* d_in, const int* in_sizes, int n_in,
                              void* d_out, int out_size, void* d_ws, size_t ws_size,
                              hipStream_t stream) {
    const float* img   = (const float*)d_in[0];   // (1, 2048, 2048) f32
    const float* noise = (const float*)d_in[1];   // (1, 4096, 4096) f32
    float* out = (float*)d_out;                   // (1, 4096, 4096) f32

    dim3 grid((N + TX - 1) / TX, (N + TY - 1) / TY);   // 74 x 74
    TensorAugment_79216376807666_kernel<<<grid, 256, 0, stream>>>(img, noise, out);
}

// Round 4
// 144.453 us; speedup vs baseline: 1.1129x; 1.1129x over previous
//
#include <hip/hip_runtime.h>
#include <math.h>

#define N     4096
#define NIMG  2048
#define TX    56          // output tile width
#define TY    32          // output tile height
#define DW    64          // D-region width  = TX + 8 (1 lane per column)
#define DH    40          // D-region height = TY + 8
#define IPR   36          // img patch rows allocated (max needed 34)
#define IPP   25          // img patch pitch (odd -> conflict-free)
#define STP   41          // ST pitch over rows (odd)
#define VP    65          // V pitch
#define S2P   57          // transpose-out pitch (odd)

// Gaussian kernel sigma=1, r=4 (double-precision eval of reference formula)
#define KW0 0.00013383063f
#define KW1 0.00443186160f
#define KW2 0.05399112800f
#define KW3 0.24197144000f
#define KW4 0.39894346870f

__device__ __forceinline__ int symi(int g) {
    g = (g < 0) ? (-1 - g) : g;
    g = (g >= N) ? (2 * N - 1 - g) : g;
    return g;
}

__global__ __launch_bounds__(256, 8)
void TensorAugment_79216376807666_kernel(const float* __restrict__ img,
                                         const float* __restrict__ noise,
                                         float* __restrict__ out) {
    __shared__ float ST[DW * STP];     // D tile col-major [c][row]; later transpose buf (10.5 KB)
    __shared__ float UN[TY * VP];      // union: IP (stages 0-1) / V (stages 2-3)      (8.3 KB)
    float* const IP = UN;
    float* const V  = UN;

    const int tid  = threadIdx.x;
    const int lane = tid & 63;
    const int wave = tid >> 6;
    const int bx = blockIdx.x, by = blockIdx.y;
    const int x0 = bx * TX;
    const int y0 = by * TY;
    // interior: x halo [x0-4, x0+59] in-range and y halo [y0-4, y0+35] in-range
    const bool interior = (bx >= 1) && (bx <= 72) && (by >= 1) && (by <= 126);

    const float kk[9] = {KW0, KW1, KW2, KW3, KW4, KW3, KW2, KW1, KW0};

    // ---- block-uniform staged img ranges (generic; exact for interior) ----
    int gxa = x0 - 4, gxb = x0 + DW - 5;
    int mxa = symi(gxa), mxb = symi(gxb);
    int gxmin = min(mxa, mxb), gxmax = max(mxa, mxb);
    if (gxa <= 0) gxmin = 0;
    if (gxb >= N - 1) gxmax = N - 1;
    int umin = (N - 1) - gxmax, umax = (N - 1) - gxmin;
    int r0min = (umin - 1) >> 1;
    int r0max = (umax - 1) >> 1;
    int nrows = r0max - r0min + 2;       // <= 34

    int gya = y0 - 4, gyb = y0 + DH - 5;
    int mya = symi(gya), myb = symi(gyb);
    int gymin = min(mya, myb), gymax = max(mya, myb);
    if (gya <= 0) gymin = 0;
    if (gyb >= N - 1) gymax = N - 1;
    int c0min = (gymin - 1) >> 1;
    int c0max = (gymax - 1) >> 1;
    int ncols = c0max - c0min + 2;       // <= 22

    // ---- stage 0: img patch -> IP (coalesced; clamps are no-ops interior) ----
    {
        int c = tid & 31;
        for (int r = tid >> 5; r < nrows; r += 8) {
            if (c < ncols) {
                int ir = min(max(r0min + r, 0), NIMG - 1);
                int ic = min(max(c0min + c, 0), NIMG - 1);
                IP[r * IPP + c] = img[ir * NIMG + ic];
            }
        }
    }
    __syncthreads();

    // ---- stage 1: D = bilinear(rot) + 0.01*noise, column-major into ST ----
    if (interior) {
        // lane g handles D cols 4g..4g+3 of one D row; quad rr picks the row.
        int g  = lane & 15;
        int rr = lane >> 4;
        int sbase = (30 - 2 * g) * IPP;           // staged img row (m-2)
        const float* npz = noise + (size_t)(y0 - 4) * N + (x0 - 4) + 4 * g;
#pragma unroll
        for (int it = 0; it < 3; ++it) {
            int row = it * 16 + wave * 4 + rr;    // 0..47; skip >=40
            if (row < DH) {
                int jc  = (row + 1) >> 1;
                float wc1 = (row & 1) ? 0.25f : 0.75f;
                float wc0 = 1.0f - wc1;
                float4 nv = *reinterpret_cast<const float4*>(npz + (size_t)row * N);
                int b = sbase + jc;
                float t0 = fmaf(wc0, IP[b],           wc1 * IP[b + 1]);            // m-2
                float t1 = fmaf(wc0, IP[b + IPP],     wc1 * IP[b + IPP + 1]);      // m-1
                float t2 = fmaf(wc0, IP[b + 2 * IPP], wc1 * IP[b + 2 * IPP + 1]);  // m
                float t3 = fmaf(wc0, IP[b + 3 * IPP], wc1 * IP[b + 3 * IPP + 1]);  // m+1
                float D0 = fmaf(0.75f, t2, 0.25f * t3);
                float D1 = fmaf(0.25f, t1, 0.75f * t2);
                float D2 = fmaf(0.75f, t1, 0.25f * t2);
                float D3 = fmaf(0.25f, t0, 0.75f * t1);
                int sb = (4 * g) * STP + row;
                ST[sb]           = fmaf(0.01f, nv.x, D0);
                ST[sb + STP]     = fmaf(0.01f, nv.y, D1);
                ST[sb + 2 * STP] = fmaf(0.01f, nv.z, D2);
                ST[sb + 3 * STP] = fmaf(0.01f, nv.w, D3);
            }
        }
    } else {
        // generic edge path (scalar, symmetric mapping)
        int c   = lane;
        int gxm = symi(x0 - 4 + c);
        int u   = (N - 1) - gxm;
        int r0  = (u - 1) >> 1;
        float wr1 = (u & 1) ? 0.25f : 0.75f;
        float wr0 = 1.0f - wr1;
        int a0 = (r0 - r0min) * IPP;
#pragma unroll
        for (int k = 0; k < 10; ++k) {
            int row = wave + 4 * k;               // 0..39
            int gym = symi(y0 - 4 + row);
            int c0  = (gym - 1) >> 1;
            float wc1 = (gym & 1) ? 0.25f : 0.75f;
            float wc0 = 1.0f - wc1;
            int jc = c0 - c0min;
            float nv = noise[gym * N + gxm];
            float f0 = IP[a0 + jc],       f1 = IP[a0 + jc + 1];
            float f2 = IP[a0 + IPP + jc], f3 = IP[a0 + IPP + jc + 1];
            float top = fmaf(wc0, f0, wc1 * f1);
            float bot = fmaf(wc0, f2, wc1 * f3);
            ST[c * STP + row] = fmaf(wr0, top, wr1 * bot) + 0.01f * nv;
        }
    }
    __syncthreads();   // ST ready; IP dead (UN reused as V below)

    // ---- stage 2: vertical blur, sliding window (8 outputs/thread) ----
    {
        int c  = lane;
        int rb = wave * 8;                        // 0,8,16,24
        float win[16];
        int ab = c * STP + rb;
#pragma unroll
        for (int k = 0; k < 16; ++k) win[k] = ST[ab + k];   // contiguous -> ds_read2
#pragma unroll
        for (int j = 0; j < 8; ++j) {
            float acc = 0.0f;
#pragma unroll
            for (int i = 0; i < 9; ++i) acc = fmaf(kk[i], win[j + i], acc);
            V[(rb + j) * VP + c] = acc;
        }
    }
    __syncthreads();

    // ---- stage 3: horizontal blur + relu + log1p -> transpose buffer ----
    {
        int r = tid >> 3;                         // 0..31
        int s = tid & 7;                          // 0..7 (7 cols each)
        float w2[15];
        int vb = r * VP + s * 7;
#pragma unroll
        for (int k = 0; k < 15; ++k) w2[k] = V[vb + k];     // contiguous -> ds_read2
#pragma unroll
        for (int j = 0; j < 7; ++j) {
            float acc = 0.0f;
#pragma unroll
            for (int i = 0; i < 9; ++i) acc = fmaf(kk[i], w2[j + i], acc);
            acc = fmaxf(acc, 0.0f);
            ST[r * S2P + s * 7 + j] = __logf(1.0f + acc);   // reuse ST
        }
    }
    __syncthreads();

    // ---- stage 4: coalesced store ----
    for (int r = wave; r < TY; r += 4) {
        int gx = x0 + lane;
        if (lane < TX && gx < N)
            out[(size_t)(y0 + r) * N + gx] = ST[r * S2P + lane];
    }
}

extern "C" void kernel_launch(void* const* d_in, const int* in_sizes, int n_in,
                              void* d_out, int out_size, void* d_ws, size_t ws_size,
                              hipStream_t stream) {
    const float* img   = (const float*)d_in[0];   // (1, 2048, 2048) f32
    const float* noise = (const float*)d_in[1];   // (1, 4096, 4096) f32
    float* out = (float*)d_out;                   // (1, 4096, 4096) f32

    dim3 grid((N + TX - 1) / TX, N / TY);         // 74 x 128 blocks
    TensorAugment_79216376807666_kernel<<<grid, 256, 0, stream>>>(img, noise, out);
}

// Round 5
// 144.035 us; speedup vs baseline: 1.1161x; 1.0029x over previous
//
#include <hip/hip_runtime.h>
#include <math.h>

#define N     4096
#define NIMG  2048
#define TX    56          // output tile width
#define TY    32          // output tile height
#define DW    64          // D-region width  = TX + 8 (1 lane per column)
#define DH    40          // D-region height = TY + 8
#define IPP   25          // img patch pitch (odd -> conflict-free)
#define STP   41          // ST pitch over rows (odd -> conflict-free: gcd(41,32)=1)
#define VP    65          // V pitch (65 -> at most 2-way, free)
#define S2P   59          // transpose-out pitch (59: no <=8-lane diagonal collisions; 57 had 8-way)
#define GBX   74          // grid blocks in x
#define GBY   128         // grid blocks in y

// Gaussian kernel sigma=1, r=4 (double-precision eval of reference formula)
#define KW0 0.00013383063f
#define KW1 0.00443186160f
#define KW2 0.05399112800f
#define KW3 0.24197144000f
#define KW4 0.39894346870f

__device__ __forceinline__ int symi(int g) {
    g = (g < 0) ? (-1 - g) : g;
    g = (g >= N) ? (2 * N - 1 - g) : g;
    return g;
}

__global__ __launch_bounds__(256, 4)
void TensorAugment_79216376807666_kernel(const float* __restrict__ img,
                                         const float* __restrict__ noise,
                                         float* __restrict__ out) {
    __shared__ float ST[DW * STP];     // D tile col-major [c][row]; later transpose buf (10.5 KB)
    __shared__ float UN[TY * VP];      // union: IP (stages 0-1) / V (stages 2-3)       (8.3 KB)
    float* const IP = UN;
    float* const V  = UN;

    const int tid  = threadIdx.x;
    const int lane = tid & 63;
    const int wave = tid >> 6;

    // ---- XCD-aware swizzle: each XCD (b&7) owns a contiguous 74x16 slab ----
    int b   = blockIdx.y * GBX + blockIdx.x;
    int xcd = b & 7;
    int i   = b >> 3;                   // 0..1183
    int bx  = i % GBX;                  // 0..73
    int by  = xcd * 16 + i / GBX;       // 0..127

    const int x0 = bx * TX;
    const int y0 = by * TY;
    const bool interior = (bx >= 1) && (bx <= 72) && (by >= 1) && (by <= 126);

    const float kk[9] = {KW0, KW1, KW2, KW3, KW4, KW3, KW2, KW1, KW0};

    // ---- interior: prefetch noise (overlaps with img staging below) ----
    const int g  = lane & 15;
    const int rr = lane >> 4;
    const int rowbase = wave * 4 + rr;           // 0..15
    float4 nv0, nv1, nv2;
    if (interior) {
        const float* npz = noise + (size_t)(y0 - 4) * N + (x0 - 4) + 4 * g;
        nv0 = *reinterpret_cast<const float4*>(npz + (size_t)rowbase * N);
        nv1 = *reinterpret_cast<const float4*>(npz + (size_t)(rowbase + 16) * N);
        if (rowbase + 32 < DH)
            nv2 = *reinterpret_cast<const float4*>(npz + (size_t)(rowbase + 32) * N);
    }

    // ---- block-uniform staged img ranges (generic; exact for interior) ----
    int gxa = x0 - 4, gxb = x0 + DW - 5;
    int mxa = symi(gxa), mxb = symi(gxb);
    int gxmin = min(mxa, mxb), gxmax = max(mxa, mxb);
    if (gxa <= 0) gxmin = 0;
    if (gxb >= N - 1) gxmax = N - 1;
    int umin = (N - 1) - gxmax, umax = (N - 1) - gxmin;
    int r0min = (umin - 1) >> 1;
    int r0max = (umax - 1) >> 1;
    int nrows = r0max - r0min + 2;       // <= 34

    int gya = y0 - 4, gyb = y0 + DH - 5;
    int mya = symi(gya), myb = symi(gyb);
    int gymin = min(mya, myb), gymax = max(mya, myb);
    if (gya <= 0) gymin = 0;
    if (gyb >= N - 1) gymax = N - 1;
    int c0min = (gymin - 1) >> 1;
    int c0max = (gymax - 1) >> 1;
    int ncols = c0max - c0min + 2;       // <= 22

    // ---- stage 0: img patch -> IP (coalesced; clamps are no-ops interior) ----
    {
        int c = tid & 31;
        for (int r = tid >> 5; r < nrows; r += 8) {
            if (c < ncols) {
                int ir = min(max(r0min + r, 0), NIMG - 1);
                int ic = min(max(c0min + c, 0), NIMG - 1);
                IP[r * IPP + c] = img[ir * NIMG + ic];
            }
        }
    }
    __syncthreads();

    // ---- stage 1: D = bilinear(rot) + 0.01*noise, column-major into ST ----
    if (interior) {
        // lane g handles D cols 4g..4g+3 of one D row; quad rr picks the row.
        int sbase = (30 - 2 * g) * IPP;           // staged img row (m-2)
        float4 nvv[3] = {nv0, nv1, nv2};
#pragma unroll
        for (int it = 0; it < 3; ++it) {
            int row = it * 16 + rowbase;          // 0..47; skip >=40
            if (row < DH) {
                int jc  = (row + 1) >> 1;
                float wc1 = (row & 1) ? 0.25f : 0.75f;
                float wc0 = 1.0f - wc1;
                float4 nv = nvv[it];
                int bofs = sbase + jc;
                float t0 = fmaf(wc0, IP[bofs],           wc1 * IP[bofs + 1]);            // m-2
                float t1 = fmaf(wc0, IP[bofs + IPP],     wc1 * IP[bofs + IPP + 1]);      // m-1
                float t2 = fmaf(wc0, IP[bofs + 2 * IPP], wc1 * IP[bofs + 2 * IPP + 1]);  // m
                float t3 = fmaf(wc0, IP[bofs + 3 * IPP], wc1 * IP[bofs + 3 * IPP + 1]);  // m+1
                float D0 = fmaf(0.75f, t2, 0.25f * t3);
                float D1 = fmaf(0.25f, t1, 0.75f * t2);
                float D2 = fmaf(0.75f, t1, 0.25f * t2);
                float D3 = fmaf(0.25f, t0, 0.75f * t1);
                int sb = (4 * g) * STP + row;
                ST[sb]           = fmaf(0.01f, nv.x, D0);
                ST[sb + STP]     = fmaf(0.01f, nv.y, D1);
                ST[sb + 2 * STP] = fmaf(0.01f, nv.z, D2);
                ST[sb + 3 * STP] = fmaf(0.01f, nv.w, D3);
            }
        }
    } else {
        // generic edge path (scalar, symmetric mapping)
        int c   = lane;
        int gxm = symi(x0 - 4 + c);
        int u   = (N - 1) - gxm;
        int r0  = (u - 1) >> 1;
        float wr1 = (u & 1) ? 0.25f : 0.75f;
        float wr0 = 1.0f - wr1;
        int a0 = (r0 - r0min) * IPP;
#pragma unroll
        for (int k = 0; k < 10; ++k) {
            int row = wave + 4 * k;               // 0..39
            int gym = symi(y0 - 4 + row);
            int c0  = (gym - 1) >> 1;
            float wc1 = (gym & 1) ? 0.25f : 0.75f;
            float wc0 = 1.0f - wc1;
            int jc = c0 - c0min;
            float nvs = noise[(size_t)gym * N + gxm];
            float f0 = IP[a0 + jc],       f1 = IP[a0 + jc + 1];
            float f2 = IP[a0 + IPP + jc], f3 = IP[a0 + IPP + jc + 1];
            float top = fmaf(wc0, f0, wc1 * f1);
            float bot = fmaf(wc0, f2, wc1 * f3);
            ST[c * STP + row] = fmaf(wr0, top, wr1 * bot) + 0.01f * nvs;
        }
    }
    __syncthreads();   // ST ready; IP dead (UN reused as V below)

    // ---- stage 2: vertical blur, sliding window (8 outputs/thread) ----
    {
        int c  = lane;
        int rb = wave * 8;                        // 0,8,16,24
        float win[16];
        int ab = c * STP + rb;
#pragma unroll
        for (int k = 0; k < 16; ++k) win[k] = ST[ab + k];   // contiguous -> ds_read2
#pragma unroll
        for (int j = 0; j < 8; ++j) {
            float acc = 0.0f;
#pragma unroll
            for (int i2 = 0; i2 < 9; ++i2) acc = fmaf(kk[i2], win[j + i2], acc);
            V[(rb + j) * VP + c] = acc;
        }
    }
    __syncthreads();

    // ---- stage 3: horizontal blur + relu + log1p -> transpose buffer ----
    {
        int r = tid >> 3;                         // 0..31
        int s = tid & 7;                          // 0..7 (7 cols each)
        float w2[15];
        int vb = r * VP + s * 7;
#pragma unroll
        for (int k = 0; k < 15; ++k) w2[k] = V[vb + k];     // contiguous -> ds_read2
#pragma unroll
        for (int j = 0; j < 7; ++j) {
            float acc = 0.0f;
#pragma unroll
            for (int i2 = 0; i2 < 9; ++i2) acc = fmaf(kk[i2], w2[j + i2], acc);
            acc = fmaxf(acc, 0.0f);
            ST[r * S2P + s * 7 + j] = __logf(1.0f + acc);   // reuse ST
        }
    }
    __syncthreads();

    // ---- stage 4: coalesced store ----
    for (int r = wave; r < TY; r += 4) {
        int gx = x0 + lane;
        if (lane < TX && gx < N)
            out[(size_t)(y0 + r) * N + gx] = ST[r * S2P + lane];
    }
}

extern "C" void kernel_launch(void* const* d_in, const int* in_sizes, int n_in,
                              void* d_out, int out_size, void* d_ws, size_t ws_size,
                              hipStream_t stream) {
    const float* img   = (const float*)d_in[0];   // (1, 2048, 2048) f32
    const float* noise = (const float*)d_in[1];   // (1, 4096, 4096) f32
    float* out = (float*)d_out;                   // (1, 4096, 4096) f32

    dim3 grid(GBX, GBY);                          // 74 x 128 blocks (swizzled in-kernel)
    TensorAugment_79216376807666_kernel<<<grid, 256, 0, stream>>>(img, noise, out);
}